// Round 18
// baseline (109.415 us; speedup 1.0000x reference)
//
#include <hip/hip_runtime.h>

typedef unsigned int u32;
typedef unsigned long long u64;

#define BB 16
#define LL 8192
#define CC 512
#define KK 64
#define LCH 256          // L-chunks per batch
#define LPB 32           // rows per chunk (bitmask width)
#define VCAP 12          // value slots per (thread=4cols x 32rows) record; P(>12) ~ 4e-8
#define THRESH 2.1f      // survivors/col: mean~146 sigma~12 -> [64,256] w/ ~7 sigma margin

#define WAVE_FENCE()                                            \
  do {                                                          \
    asm volatile("s_waitcnt lgkmcnt(0)" ::: "memory");          \
    __builtin_amdgcn_sched_barrier(0);                          \
  } while (0)

// ---- order-preserving fp32 <-> u32 key transforms ----
__device__ __forceinline__ u32 flip_bits(u32 u) {
  return u ^ ((u & 0x80000000u) ? 0xFFFFFFFFu : 0x80000000u);
}
__device__ __forceinline__ u32 unflip_bits(u32 f) {
  return (f & 0x80000000u) ? (f ^ 0x80000000u) : ~f;
}
__device__ __forceinline__ u64 u64max(u64 a, u64 b) { return a > b ? a : b; }

// ---------------- Kernel A: R2 stream geometry + dense value store ----------------
// Unchanged full-row streaming (R2-proven). NEW: survivors appended to a
// per-thread LDS buffer (per-lane independent predicated ds_write — no
// ballots/atomics, unlike R4's collapse), then copied out coalesced as SoA
// vws[chunk][slot][tid]. Append order = (row, col) lex -> B recomputes slots
// from mask prefix-popcounts. Cap VCAP/record; overflow detected in B.
__global__ __launch_bounds__(128) void kbitmask(const float* __restrict__ x,
                                                u32* __restrict__ bm,
                                                float* __restrict__ vws) {
  __shared__ float vbuf[128][13];   // pad 13: bank-spread for fixed-slot column reads
  int blk = blockIdx.x;
  int b = blk >> 8;
  int chunk = blk & (LCH - 1);
  int t = threadIdx.x;
  const float4* p =
      reinterpret_cast<const float4*>(x + ((size_t)b * LL + (size_t)chunk * LPB) * CC) + t;
  u32 m0 = 0, m1 = 0, m2 = 0, m3 = 0;
  u32 cnt = 0;
#pragma unroll
  for (int i = 0; i < LPB; ++i) {
    float4 v = p[(size_t)i * (CC / 4)];
    bool p0 = v.x > THRESH, p1 = v.y > THRESH, p2 = v.z > THRESH, p3 = v.w > THRESH;
    m0 |= ((u32)p0) << i;
    m1 |= ((u32)p1) << i;
    m2 |= ((u32)p2) << i;
    m3 |= ((u32)p3) << i;
    if (p0) { if (cnt < VCAP) vbuf[t][cnt] = v.x; cnt++; }
    if (p1) { if (cnt < VCAP) vbuf[t][cnt] = v.y; cnt++; }
    if (p2) { if (cnt < VCAP) vbuf[t][cnt] = v.z; cnt++; }
    if (p3) { if (cnt < VCAP) vbuf[t][cnt] = v.w; cnt++; }
  }
  uint4* dst = reinterpret_cast<uint4*>(bm + (size_t)(b * LCH + chunk) * CC) + t;
  *dst = make_uint4(m0, m1, m2, m3);
  WAVE_FENCE();
  // coalesced SoA copy-out: slot-major, tid-minor
  size_t vb = (size_t)(b * LCH + chunk) * (VCAP * 128) + t;
#pragma unroll
  for (int s = 0; s < VCAP; ++s) vws[vb + (size_t)s * 128] = vbuf[t][s];
}

// ---------------- Kernel B: R15 block-per-column histogram select, NO x-gather ----------------
// Identical to R15 except phase 3: values come from vws via exact slot index
// (prefix-popcount of the record's 4 mask words in (row,col) order) instead of
// scattered 64B-line gathers from x. Record popcsum > VCAP -> slow path.
__global__ __launch_bounds__(256) void kselect(const float* __restrict__ x,
                                               const u32* __restrict__ bm,
                                               const float* __restrict__ vws,
                                               float* __restrict__ out,
                                               int force_slow) {
  __shared__ u64 wl[256];
  __shared__ u32 wsum[4];
  __shared__ u32 wsum2[4];
  __shared__ u64 selbal[4];
  __shared__ u32 hist[256];
  __shared__ u32 shist[256];
  __shared__ u64 cand[64];
  __shared__ u32 ccnt;
  __shared__ int scb;
  __shared__ int bad;
  int t = threadIdx.x;
  int lane = t & 63;
  int w = t >> 6;
  // XCD-colocating bijection (R14-proven)
  int bid = blockIdx.x;
  int xcd = bid & 7;
  int iox = bid >> 3;
  int g = (iox >> 4) * 8 + xcd;
  int ch = g * 16 + (iox & 15);
  int b = ch >> 9;
  int c = ch & (CC - 1);
  int T = c >> 2;                 // record index within chunk
  int q = c & 3;                  // column within record
  const float* colp = x + (size_t)b * LL * CC + c;
  const u64 ltmask = (1ull << lane) - 1ull;

  if (t == 0) bad = force_slow;
  wl[t] = 0;
  __syncthreads();

  u32 total = 0;
  if (!force_slow) {
    // phase 1: record's 4 mask words (same 64B line as before, 16B used)
    uint4 mv = *reinterpret_cast<const uint4*>(
        bm + ((size_t)(b * LCH) + (u32)t) * CC + 4 * T);
    u32 mk = (q == 0) ? mv.x : (q == 1) ? mv.y : (q == 2) ? mv.z : mv.w;
    u32 popcsum = __popc(mv.x) + __popc(mv.y) + __popc(mv.z) + __popc(mv.w);
    if (popcsum > (u32)VCAP) bad = 1;  // record overflowed A's value buffer
    u32 cnt = __popc(mk);
    // phase 2: block exclusive scan
    u32 inc = cnt;
#pragma unroll
    for (int d = 1; d < 64; d <<= 1) {
      u32 o = __shfl_up(inc, d, 64);
      if (lane >= d) inc += o;
    }
    if (lane == 63) wsum[w] = inc;
    __syncthreads();
    u32 woff = 0;
#pragma unroll
    for (int i = 0; i < 4; ++i) {
      u32 s = wsum[i];
      woff += (i < w) ? s : 0u;
      total += s;
    }
    u32 pos = woff + inc - cnt;
    // phase 3: static 8-slot extraction + dense vws reads via slot mapping
    u32 rows_[8];
    u32 slots_[8];
    float vals_[8];
    u32 vbits = 0;
    u32 m = mk;
    u32 base = (u32)t * LPB;
#pragma unroll
    for (int s = 0; s < 8; ++s) {
      u32 bit = __builtin_ctz(m | 0x80000000u);
      vbits |= ((m != 0u) ? 1u : 0u) << s;
      rows_[s] = base + bit;
      u32 below = (1u << bit) - 1u;  // bit<=31; bit==31 -> 0x7FFFFFFF
      u32 sl = __popc(mv.x & below) + __popc(mv.y & below) + __popc(mv.z & below) +
               __popc(mv.w & below);
      if (q > 0) sl += (mv.x >> bit) & 1u;
      if (q > 1) sl += (mv.y >> bit) & 1u;
      if (q > 2) sl += (mv.z >> bit) & 1u;
      slots_[s] = sl;
      m &= m - 1;
    }
    if (m) bad = 1;  // >8 survivors in one word (P ~ 1e-8/word)
    size_t vrec = (size_t)(b * LCH + t) * (VCAP * 128) + (u32)T;
#pragma unroll
    for (int s = 0; s < 8; ++s)
      vals_[s] = ((vbits >> s) & 1u)
                     ? __builtin_nontemporal_load(vws + vrec + (size_t)slots_[s] * 128)
                     : 0.0f;
    __builtin_amdgcn_sched_barrier(0);
    // phase 4: row-ordered key write
#pragma unroll
    for (int s = 0; s < 8; ++s) {
      if ((vbits >> s) & 1u) {
        if (pos < 256)
          wl[pos] = (((u64)flip_bits(__float_as_uint(vals_[s]))) << 32) | rows_[s];
        else
          bad = 1;
        pos++;
      }
    }
  }
  __syncthreads();

  bool pre_ok = (bad == 0) && total >= (u32)KK && total <= 256u;  // block-uniform
  u64 mykey = 0;
  bool selp = false;
  if (pre_ok) {
    mykey = (t < (int)total) ? wl[t] : 0ull;
    u32 top = (u32)(mykey >> 32);
    u32 mybkt = (top >> 17) & 0xFFu;  // monotone 8-bit bucket for values in [2,16)
    hist[t] = 0;
    if (t == 0) { ccnt = 0; scb = 0; }
    __syncthreads();
    if (t < (int)total) {
      if (top >= 0xC1800000u) bad = 1;  // value >= 16: bucket would wrap
      atomicAdd(&hist[mybkt], 1u);
    }
    __syncthreads();
    // suffix scan: thread t scans bucket rev = 255-t
    int rev = 255 - t;
    u32 v = hist[rev];
    u32 inc2 = v;
#pragma unroll
    for (int d = 1; d < 64; d <<= 1) {
      u32 o = __shfl_up(inc2, d, 64);
      if (lane >= d) inc2 += o;
    }
    if (lane == 63) wsum2[w] = inc2;
    __syncthreads();
    u32 add = 0;
#pragma unroll
    for (int i = 0; i < 4; ++i) add += (i < w) ? wsum2[i] : 0u;
    shist[rev] = inc2 + add;  // count of keys with bucket >= rev
    __syncthreads();
    u32 s_t = shist[t];
    u32 s_t1 = (t == 255) ? 0u : shist[t + 1];
    if (s_t >= (u32)KK && s_t1 < (u32)KK) scb = t;
    __syncthreads();
    int cb = scb;
    u32 S = (cb == 255) ? 0u : shist[cb + 1];  // definitively selected
    u32 need = (u32)KK - S;
    bool incb = (t < (int)total) && (mybkt == (u32)cb);
    if (incb) {
      u32 ci = atomicAdd(&ccnt, 1u);
      if (ci < 64u) cand[ci] = mykey;
      else bad = 1;
    }
    __syncthreads();
    u32 rkb = 0;
    if (incb) {
      u32 nc = ccnt > 64u ? 64u : ccnt;
      for (u32 j = 0; j < nc; ++j) rkb += (cand[j] > mykey) ? 1u : 0u;
    }
    selp = (t < (int)total) && ((mybkt > (u32)cb) || (incb && rkb < need));
    __syncthreads();  // make late bad-writes visible
  }

  bool fastok = pre_ok && (bad == 0);
  if (fastok) {
    // phase 6: output position = selected-count before me (wl order = row order)
    u64 bw = __ballot(selp);
    if (lane == 0) selbal[w] = bw;
    __syncthreads();
    if (selp) {
      u32 op = (u32)__popcll(bw & ltmask);
#pragma unroll
      for (int i = 0; i < 4; ++i) op += (i < w) ? (u32)__popcll(selbal[i]) : 0u;
      out[((size_t)b * KK + op) * CC + c] =
          __uint_as_float(unflip_bits((u32)(mykey >> 32)));
    }
  } else if (w == 0) {
    // exact slow path (wave 0): reads x directly; rare backstop
    u64 prev = ~0ull;
    u64 sel = 0;
    for (int r = 0; r < KK; ++r) {
      u64 local = 0;
      for (int tt = 0; tt < LL / 64; ++tt) {
        int l = tt * 64 + lane;
        float v = colp[(size_t)l * CC];
        u64 key = (((u64)flip_bits(__float_as_uint(v))) << 32) | (u32)l;
        if (key < prev) local = u64max(local, key);
      }
#pragma unroll
      for (int mm = 32; mm > 0; mm >>= 1) local = u64max(local, __shfl_xor(local, mm, 64));
      if (lane == r) sel = local;
      prev = local;
    }
    u32 f = (u32)(sel >> 32);
    u32 l = (u32)sel;
    u64 s2 = (((u64)l) << 32) | f;
#pragma unroll
    for (int k = 2; k <= 64; k <<= 1) {
#pragma unroll
      for (int j = k >> 1; j > 0; j >>= 1) {
        u64 other = __shfl_xor(s2, j, 64);
        bool upper = (lane & j) != 0;
        bool ascb = ((lane & k) == 0);
        bool keepmax = ascb ? upper : !upper;
        u64 mx = (s2 > other) ? s2 : other;
        u64 mn = (s2 > other) ? other : s2;
        s2 = keepmax ? mx : mn;
      }
    }
    out[((size_t)b * KK + lane) * CC + c] = __uint_as_float(unflip_bits((u32)s2));
  }
}

extern "C" void kernel_launch(void* const* d_in, const int* in_sizes, int n_in,
                              void* d_out, int out_size, void* d_ws, size_t ws_size,
                              hipStream_t stream) {
  const float* x = (const float*)d_in[0];
  float* out = (float*)d_out;
  const size_t bm_bytes = (size_t)BB * LCH * CC * sizeof(u32);            // 8 MB
  const size_t vws_bytes = (size_t)BB * LCH * VCAP * 128 * sizeof(float); // 25 MB
  if (d_ws != nullptr && ws_size >= bm_bytes + vws_bytes) {
    u32* bm = (u32*)d_ws;
    float* vws = (float*)((char*)d_ws + bm_bytes);
    kbitmask<<<BB * LCH, 128, 0, stream>>>(x, bm, vws);
    kselect<<<BB * CC, 256, 0, stream>>>(x, bm, vws, out, 0);
  } else {
    kselect<<<BB * CC, 256, 0, stream>>>(x, nullptr, nullptr, out, 1);
  }
}

// Round 19
// 77.646 us; speedup vs baseline: 1.4091x; 1.4091x over previous
//
#include <hip/hip_runtime.h>

typedef unsigned int u32;
typedef unsigned long long u64;

#define BB 16
#define LL 8192
#define CC 512
#define KK 64
#define LCH 256          // L-chunks per batch
#define LPB 32           // rows per chunk (bitmask width)
#define THRESH 2.1f      // survivors/col: mean~146 sigma~12 -> [64,256] w/ ~7 sigma margin

// ---- order-preserving fp32 <-> u32 key transforms ----
__device__ __forceinline__ u32 flip_bits(u32 u) {
  return u ^ ((u & 0x80000000u) ? 0xFFFFFFFFu : 0x80000000u);
}
__device__ __forceinline__ u32 unflip_bits(u32 f) {
  return (f & 0x80000000u) ? (f ^ 0x80000000u) : ~f;
}
__device__ __forceinline__ u64 u64max(u64 a, u64 b) { return a > b ? a : b; }
__device__ __forceinline__ u64 u64min(u64 a, u64 b) { return a < b ? a : b; }

// ---------------- Kernel A (R2-proven, at roofline ~40us): DO NOT TOUCH ----------------
__global__ __launch_bounds__(128) void kbitmask(const float* __restrict__ x,
                                                u32* __restrict__ bm) {
  int blk = blockIdx.x;
  int b = blk >> 8;
  int chunk = blk & (LCH - 1);
  int t = threadIdx.x;
  const float4* p =
      reinterpret_cast<const float4*>(x + ((size_t)b * LL + (size_t)chunk * LPB) * CC) + t;
  u32 m0 = 0, m1 = 0, m2 = 0, m3 = 0;
#pragma unroll
  for (int i = 0; i < LPB; ++i) {
    float4 v = p[(size_t)i * (CC / 4)];
    m0 |= ((u32)(v.x > THRESH)) << i;
    m1 |= ((u32)(v.y > THRESH)) << i;
    m2 |= ((u32)(v.z > THRESH)) << i;
    m3 |= ((u32)(v.w > THRESH)) << i;
  }
  uint4* dst = reinterpret_cast<uint4*>(bm + (size_t)(b * LCH + chunk) * CC) + t;
  *dst = make_uint4(m0, m1, m2, m3);
}

// ---------------- Kernel B (R15-proven best): block-per-column + histogram select ----------------
__global__ __launch_bounds__(256) void kselect(const float* __restrict__ x,
                                               const u32* __restrict__ bm,
                                               float* __restrict__ out,
                                               int force_slow) {
  __shared__ u64 wl[256];
  __shared__ u32 wsum[4];
  __shared__ u32 wsum2[4];
  __shared__ u64 selbal[4];
  __shared__ u32 hist[256];
  __shared__ u32 shist[256];
  __shared__ u64 cand[64];
  __shared__ u32 ccnt;
  __shared__ int scb;
  __shared__ int bad;
  int t = threadIdx.x;
  int lane = t & 63;
  int w = t >> 6;
  // XCD-colocating bijection (R14-proven): 16-col line-group -> one XCD's L2
  int bid = blockIdx.x;
  int xcd = bid & 7;
  int iox = bid >> 3;
  int g = (iox >> 4) * 8 + xcd;
  int ch = g * 16 + (iox & 15);
  int b = ch >> 9;
  int c = ch & (CC - 1);
  const float* colp = x + (size_t)b * LL * CC + c;
  const u64 ltmask = (1ull << lane) - 1ull;

  if (t == 0) bad = force_slow;
  wl[t] = 0;
  __syncthreads();

  u32 total = 0;
  if (!force_slow) {
    // phase 1: one mask word per thread
    u32 mw = bm[((size_t)(b * LCH) + (u32)t) * CC + c];
    u32 cnt = __popc(mw);
    // phase 2: block exclusive scan
    u32 inc = cnt;
#pragma unroll
    for (int d = 1; d < 64; d <<= 1) {
      u32 o = __shfl_up(inc, d, 64);
      if (lane >= d) inc += o;
    }
    if (lane == 63) wsum[w] = inc;
    __syncthreads();
    u32 woff = 0;
#pragma unroll
    for (int i = 0; i < 4; ++i) {
      u32 s = wsum[i];
      woff += (i < w) ? s : 0u;
      total += s;
    }
    u32 pos = woff + inc - cnt;
    // phase 3: static 8-slot extraction + one batch of independent NT loads
    u32 rows_[8];
    float vals_[8];
    u32 vbits = 0;
    u32 m = mw;
    u32 base = (u32)t * LPB;
#pragma unroll
    for (int s = 0; s < 8; ++s) {
      u32 bit = __builtin_ctz(m | 0x80000000u);
      vbits |= ((m != 0u) ? 1u : 0u) << s;
      rows_[s] = base + bit;
      m &= m - 1;
    }
    if (m) bad = 1;  // >8 survivors in one word (P ~ 1e-8/word)
#pragma unroll
    for (int s = 0; s < 8; ++s)
      vals_[s] = ((vbits >> s) & 1u)
                     ? __builtin_nontemporal_load(colp + (size_t)rows_[s] * CC)
                     : 0.0f;
    __builtin_amdgcn_sched_barrier(0);
    // phase 4: row-ordered key write
#pragma unroll
    for (int s = 0; s < 8; ++s) {
      if ((vbits >> s) & 1u) {
        if (pos < 256)
          wl[pos] = (((u64)flip_bits(__float_as_uint(vals_[s]))) << 32) | rows_[s];
        else
          bad = 1;
        pos++;
      }
    }
  }
  __syncthreads();

  bool pre_ok = (bad == 0) && total >= (u32)KK && total <= 256u;  // block-uniform
  u64 mykey = 0;
  bool selp = false;
  if (pre_ok) {
    mykey = (t < (int)total) ? wl[t] : 0ull;
    u32 top = (u32)(mykey >> 32);
    u32 mybkt = (top >> 17) & 0xFFu;  // monotone 8-bit bucket for values in [2,16)
    hist[t] = 0;
    if (t == 0) { ccnt = 0; scb = 0; }
    __syncthreads();
    if (t < (int)total) {
      if (top >= 0xC1800000u) bad = 1;  // value >= 16: bucket would wrap
      atomicAdd(&hist[mybkt], 1u);
    }
    __syncthreads();
    // suffix scan: thread t scans bucket rev = 255-t (descending buckets)
    int rev = 255 - t;
    u32 v = hist[rev];
    u32 inc2 = v;
#pragma unroll
    for (int d = 1; d < 64; d <<= 1) {
      u32 o = __shfl_up(inc2, d, 64);
      if (lane >= d) inc2 += o;
    }
    if (lane == 63) wsum2[w] = inc2;
    __syncthreads();
    u32 add = 0;
#pragma unroll
    for (int i = 0; i < 4; ++i) add += (i < w) ? wsum2[i] : 0u;
    shist[rev] = inc2 + add;  // = count of keys with bucket >= rev
    __syncthreads();
    // cutoff bucket: unique t with shist[t] >= KK and shist[t+1] < KK
    u32 s_t = shist[t];
    u32 s_t1 = (t == 255) ? 0u : shist[t + 1];
    if (s_t >= (u32)KK && s_t1 < (u32)KK) scb = t;
    __syncthreads();
    int cb = scb;
    u32 S = (cb == 255) ? 0u : shist[cb + 1];  // definitively selected
    u32 need = (u32)KK - S;                    // >= 1
    bool incb = (t < (int)total) && (mybkt == (u32)cb);
    if (incb) {
      u32 ci = atomicAdd(&ccnt, 1u);
      if (ci < 64u) cand[ci] = mykey;
      else bad = 1;
    }
    __syncthreads();
    u32 rkb = 0;
    if (incb) {
      u32 nc = ccnt > 64u ? 64u : ccnt;
      for (u32 j = 0; j < nc; ++j) rkb += (cand[j] > mykey) ? 1u : 0u;
    }
    selp = (t < (int)total) && ((mybkt > (u32)cb) || (incb && rkb < need));
    __syncthreads();  // make late bad-writes visible
  }

  bool fastok = pre_ok && (bad == 0);
  if (fastok) {
    // phase 6: output position = selected-count before me (wl order = row order)
    u64 bw = __ballot(selp);
    if (lane == 0) selbal[w] = bw;
    __syncthreads();
    if (selp) {
      u32 op = (u32)__popcll(bw & ltmask);
#pragma unroll
      for (int i = 0; i < 4; ++i) op += (i < w) ? (u32)__popcll(selbal[i]) : 0u;
      out[((size_t)b * KK + op) * CC + c] =
          __uint_as_float(unflip_bits((u32)(mykey >> 32)));
    }
  } else if (w == 0) {
    // exact slow path (wave 0): 64 rounds of wave-reduce max, then index sort
    u64 prev = ~0ull;
    u64 sel = 0;
    for (int r = 0; r < KK; ++r) {
      u64 local = 0;
      for (int tt = 0; tt < LL / 64; ++tt) {
        int l = tt * 64 + lane;
        float v = colp[(size_t)l * CC];
        u64 key = (((u64)flip_bits(__float_as_uint(v))) << 32) | (u32)l;
        if (key < prev) local = u64max(local, key);
      }
#pragma unroll
      for (int mm = 32; mm > 0; mm >>= 1) local = u64max(local, __shfl_xor(local, mm, 64));
      if (lane == r) sel = local;
      prev = local;
    }
    u32 f = (u32)(sel >> 32);
    u32 l = (u32)sel;
    u64 s2 = (((u64)l) << 32) | f;
#pragma unroll
    for (int k = 2; k <= 64; k <<= 1) {
#pragma unroll
      for (int j = k >> 1; j > 0; j >>= 1) {
        u64 other = __shfl_xor(s2, j, 64);
        bool upper = (lane & j) != 0;
        bool ascb = ((lane & k) == 0);
        bool keepmax = ascb ? upper : !upper;
        s2 = keepmax ? u64max(s2, other) : u64min(s2, other);
      }
    }
    out[((size_t)b * KK + lane) * CC + c] = __uint_as_float(unflip_bits((u32)s2));
  }
}

extern "C" void kernel_launch(void* const* d_in, const int* in_sizes, int n_in,
                              void* d_out, int out_size, void* d_ws, size_t ws_size,
                              hipStream_t stream) {
  const float* x = (const float*)d_in[0];
  float* out = (float*)d_out;
  const size_t need = (size_t)BB * LCH * CC * sizeof(u32);  // 8 MB of bitmasks
  if (d_ws != nullptr && ws_size >= need) {
    u32* bm = (u32*)d_ws;
    kbitmask<<<BB * LCH, 128, 0, stream>>>(x, bm);
    kselect<<<BB * CC, 256, 0, stream>>>(x, bm, out, 0);
  } else {
    kselect<<<BB * CC, 256, 0, stream>>>(x, nullptr, out, 1);
  }
}